// Round 8
// baseline (1023.866 us; speedup 1.0000x reference)
//
#include <hip/hip_runtime.h>

#define HID 256
#define NB 1024
#define NACT 16

typedef __bf16 bf16x8 __attribute__((ext_vector_type(8)));
typedef float  f32x4  __attribute__((ext_vector_type(4)));

// LDS map: hA hi 32K | hA lo 32K | Wt 16K (Wh-half 8K + Wl-half 8K). Total 80 KB.
#define HA_LO   32768
#define WT_OFF  65536
#define LDS_TOT 81920
// overlays in Wt region (live only between kqloops):
//   Sp f32[512] @WT_OFF ; Sf f32[256] @+2048 ; Tp f32[256] @+3072 ; Dp f32[4096] @WT_OFF
#define SP_OFF  WT_OFF
#define SF_OFF  (WT_OFF + 2048)
#define TP_OFF  (WT_OFF + 3072)
#define DP_OFF  WT_OFF

#define PREP_N (4 * 65536 + 4096)

__device__ __forceinline__ void gload_lds16(const void* g, void* l) {
    __builtin_amdgcn_global_load_lds(
        (const __attribute__((address_space(1))) void*)g,
        (__attribute__((address_space(3))) void*)l, 16, 0, 0);
}
__device__ __forceinline__ unsigned short f2bf(float x) {
    union { float f; unsigned u; } v; v.f = x;
    unsigned r = v.u + 0x7fff + ((v.u >> 16) & 1);
    return (unsigned short)(r >> 16);
}
__device__ __forceinline__ float bf2f(unsigned short b) {
    union { float f; unsigned u; } v; v.u = ((unsigned)b) << 16;
    return v.f;
}
__device__ __forceinline__ float b2f_lo(unsigned v) { return bf2f((unsigned short)(v & 0xffffu)); }
__device__ __forceinline__ float b2f_hi(unsigned v) { return bf2f((unsigned short)(v >> 16)); }

// ---- prep: all weights stored [n][k] (row = output col, 256 k), hi/lo pairs ----
// WA = Aw = W1h - inv*W1c ; WH = W1h0 ; WB = W2 ; WD[a][k] = Wd ; Wc f32 [k][n]
__global__ __launch_bounds__(256) void prep_k(const float* __restrict__ W1,
                                              const float* __restrict__ W2,
                                              const float* __restrict__ Wd,
                                              unsigned short* __restrict__ WAh, unsigned short* __restrict__ WAl,
                                              unsigned short* __restrict__ WHh, unsigned short* __restrict__ WHl,
                                              unsigned short* __restrict__ WBh, unsigned short* __restrict__ WBl,
                                              unsigned short* __restrict__ WDh, unsigned short* __restrict__ WDl,
                                              float* __restrict__ Wc) {
    int i = blockIdx.x * 256 + threadIdx.x;
    const float inv = 1.0f / 63.0f;
    if (i < 65536) {
        int n = i >> 8, k = i & 255;
        float val = W1[k * 256 + n] - inv * W1[(256 + k) * 256 + n];
        unsigned short hi = f2bf(val);
        WAh[i] = hi; WAl[i] = f2bf(val - bf2f(hi));
    } else if (i < 2 * 65536) {
        int j = i - 65536, n = j >> 8, k = j & 255;
        float val = W1[(512 + k) * 256 + n];
        unsigned short hi = f2bf(val);
        WHh[j] = hi; WHl[j] = f2bf(val - bf2f(hi));
    } else if (i < 3 * 65536) {
        int j = i - 2 * 65536, n = j >> 8, k = j & 255;
        float val = W2[k * 256 + n];
        unsigned short hi = f2bf(val);
        WBh[j] = hi; WBl[j] = f2bf(val - bf2f(hi));
    } else if (i < 4 * 65536) {
        int j = i - 3 * 65536, k = j >> 8, n = j & 255;
        Wc[j] = inv * W1[(256 + k) * 256 + n];
    } else if (i < PREP_N) {
        int j = i - 4 * 65536, a = j >> 8, k = j & 255;
        float val = Wd[k * 16 + a];
        unsigned short hi = f2bf(val);
        WDh[j] = hi; WDl[j] = f2bf(val - bf2f(hi));
    }
}

// ---- dual-tile kq loop: acc[hf][ni][mi] += (W^T)·(h^T) with frag reuse ----
// Per kq (K=32 chunk): read h-frags hi/lo once (8 b128), stage Wh/Wl half-tiles
// (n-halves of 128), 3 MFMA per acc: hi*Wh + hi*Wl + lo*Wh.
__device__ __forceinline__ void kqloop(const unsigned short* __restrict__ Wh,
                                       const unsigned short* __restrict__ Wl,
                                       char* lds, f32x4 (&acc)[2][2][4],
                                       int tid, int w, int l15, int g)
{
    char* hA = lds;
    char* Wt = lds + WT_OFF;
    const int rx = (l15 & 7) << 4;
    for (int kq = 0; kq < 8; ++kq) {
        // h-fragments for this K-chunk (shared by both halves) — hA is stable
        bf16x8 hfh[4], hfl[4];
        #pragma unroll
        for (int mi = 0; mi < 4; ++mi) {
            int mbyte = (mi * 16 + l15) * 512 + ((kq * 64 + g * 16) ^ rx);
            hfh[mi] = *(const bf16x8*)(hA + mbyte);
            hfl[mi] = *(const bf16x8*)(hA + HA_LO + mbyte);
        }
        #pragma unroll
        for (int hf = 0; hf < 2; ++hf) {
            __syncthreads();                       // Wt free (prior readers done)
            #pragma unroll
            for (int p = 0; p < 4; ++p) {
                int c  = p * 256 + tid;
                int cw = c & 511;
                int n  = cw >> 2;
                int sp = (cw & 3) ^ ((n >> 1) & 3);
                const unsigned short* src = (p < 2) ? Wh : Wl;
                gload_lds16(src + (size_t)(hf * 128 + n) * 256 + kq * 32 + sp * 8,
                            Wt + ((p < 2) ? 0 : 8192) + cw * 16);
            }
            __syncthreads();                       // staged (barrier drains vmcnt)
            #pragma unroll
            for (int ni = 0; ni < 2; ++ni) {
                int nl = w * 32 + ni * 16 + l15;
                int wb = nl * 64 + ((g ^ ((nl >> 1) & 3)) << 4);
                bf16x8 wfh = *(const bf16x8*)(Wt + wb);
                bf16x8 wfl = *(const bf16x8*)(Wt + 8192 + wb);
                #pragma unroll
                for (int mi = 0; mi < 4; ++mi) {
                    acc[hf][ni][mi] = __builtin_amdgcn_mfma_f32_16x16x32_bf16(wfh, hfh[mi], acc[hf][ni][mi], 0, 0, 0);
                    acc[hf][ni][mi] = __builtin_amdgcn_mfma_f32_16x16x32_bf16(wfl, hfh[mi], acc[hf][ni][mi], 0, 0, 0);
                    acc[hf][ni][mi] = __builtin_amdgcn_mfma_f32_16x16x32_bf16(wfh, hfl[mi], acc[hf][ni][mi], 0, 0, 0);
                }
            }
        }
    }
    // NOTE: no trailing barrier — caller must sync before writing hA / reusing Wt
}

// ---- S/T: T[n] = (sum_rows h) @ Wc  (256 threads; Wt overlay) ----
__device__ __forceinline__ void STfun(char* lds, const float* __restrict__ Wc, int tid)
{
    char* hA = lds;
    float* Sp = (float*)(lds + SP_OFF);
    float* Sf = (float*)(lds + SF_OFF);
    float* Tp = (float*)(lds + TP_OFF);
    __syncthreads();                 // h writes visible; Wt region free
    {
        int np = tid & 127, mh = tid >> 7;
        float s0 = 0.f, s1 = 0.f;
        #pragma unroll 8
        for (int m = mh * 32; m < mh * 32 + 32; ++m) {
            int byte = m * 512 + ((np * 4) ^ ((m & 7) << 4));
            unsigned vh = *(const unsigned*)(hA + byte);
            unsigned vl = *(const unsigned*)(hA + HA_LO + byte);
            s0 += b2f_lo(vh) + b2f_lo(vl);
            s1 += b2f_hi(vh) + b2f_hi(vl);
        }
        Sp[mh * 256 + np * 2]     = s0;
        Sp[mh * 256 + np * 2 + 1] = s1;
    }
    __syncthreads();
    Sf[tid] = Sp[tid] + Sp[256 + tid];
    __syncthreads();
    {
        float a = 0.f;
        #pragma unroll 8
        for (int k = 0; k < 256; ++k) a += Sf[k] * Wc[(k << 8) + tid];
        Tp[tid] = a;
    }
    __syncthreads();                 // Tp visible
}

// ---- whole network, one batch per block (256 threads, 4 waves, 2 blocks/CU) ----
__global__ __launch_bounds__(256, 2) void fused_all(
    const int* __restrict__ ids, const float* __restrict__ emb,
    const unsigned short* __restrict__ WAh, const unsigned short* __restrict__ WAl,
    const unsigned short* __restrict__ WHh, const unsigned short* __restrict__ WHl,
    const unsigned short* __restrict__ WBh, const unsigned short* __restrict__ WBl,
    const unsigned short* __restrict__ WDh, const unsigned short* __restrict__ WDl,
    const float* __restrict__ Wc,
    const float* __restrict__ b1, const float* __restrict__ b2,
    const float* __restrict__ bd, float* __restrict__ out)
{
    __shared__ __align__(16) char lds[LDS_TOT];
    const int tid = threadIdx.x;
    const int lane = tid & 63;
    const int w = tid >> 6;              // wave 0..3: n-sub-slice owner
    const int l15 = lane & 15, g = lane >> 4;
    const size_t rowbase = (size_t)blockIdx.x * 64;
    char* hA = lds;
    float* Tp = (float*)(lds + TP_OFF);

    // ---- stage h0 = emb[ids] -> split hi/lo, XOR-swizzled ----
    {
        int r = tid >> 2, c0q = (tid & 3) * 64;
        int rxw = (r & 7) << 4;
        const float4* src = (const float4*)(emb + (size_t)ids[rowbase + r] * HID + c0q);
        char* dh = hA + r * 512;
        char* dl = dh + HA_LO;
        #pragma unroll
        for (int j = 0; j < 16; ++j) {
            float4 v = src[j];
            unsigned short h0 = f2bf(v.x), h1 = f2bf(v.y), h2 = f2bf(v.z), h3 = f2bf(v.w);
            unsigned short q0 = f2bf(v.x - bf2f(h0)), q1 = f2bf(v.y - bf2f(h1)),
                           q2 = f2bf(v.z - bf2f(h2)), q3 = f2bf(v.w - bf2f(h3));
            int byte = ((c0q + j * 4) * 2) ^ rxw;
            *(uint2*)(dh + byte) = make_uint2((unsigned)h0 | ((unsigned)h1 << 16),
                                              (unsigned)h2 | ((unsigned)h3 << 16));
            *(uint2*)(dl + byte) = make_uint2((unsigned)q0 | ((unsigned)q1 << 16),
                                              (unsigned)q2 | ((unsigned)q3 << 16));
        }
    }

    STfun(lds, Wc, tid);
    f32x4 tvr[2][2];
    #pragma unroll
    for (int hf = 0; hf < 2; ++hf)
        #pragma unroll
        for (int ni = 0; ni < 2; ++ni)
            tvr[hf][ni] = *(const f32x4*)(Tp + hf * 128 + w * 32 + ni * 16 + g * 4);

    f32x4 acc[2][2][4], u0r[2][2][4];
    #pragma unroll
    for (int hf = 0; hf < 2; ++hf)
        #pragma unroll
        for (int ni = 0; ni < 2; ++ni)
            #pragma unroll
            for (int mi = 0; mi < 4; ++mi) acc[hf][ni][mi] = (f32x4){0.f, 0.f, 0.f, 0.f};

    for (int s = 0; s < 4; ++s) {
        if (s == 0) {
            // u0 = h0 @ W1h0^T + b1   (hA currently holds h0)
            kqloop(WHh, WHl, lds, acc, tid, w, l15, g);
            #pragma unroll
            for (int hf = 0; hf < 2; ++hf)
                #pragma unroll
                for (int ni = 0; ni < 2; ++ni) {
                    int n0 = hf * 128 + w * 32 + ni * 16 + g * 4;
                    f32x4 b1v = *(const f32x4*)(b1 + n0);
                    #pragma unroll
                    for (int mi = 0; mi < 4; ++mi) {
                        u0r[hf][ni][mi] = acc[hf][ni][mi] + b1v;
                        acc[hf][ni][mi] = (f32x4){0.f, 0.f, 0.f, 0.f};
                    }
                }
        }
        // ---- phase A: acc = T + u0 + h @ Aw^T ----
        #pragma unroll
        for (int hf = 0; hf < 2; ++hf)
            #pragma unroll
            for (int ni = 0; ni < 2; ++ni)
                #pragma unroll
                for (int mi = 0; mi < 4; ++mi)
                    acc[hf][ni][mi] = tvr[hf][ni] + u0r[hf][ni][mi];
        kqloop(WAh, WAl, lds, acc, tid, w, l15, g);

        // ---- epilogue A: act = relu(acc) -> hA ; acc := hres + b2 ----
        __syncthreads();                 // all phase-A hA/Wt readers done
        #pragma unroll
        for (int hf = 0; hf < 2; ++hf)
            #pragma unroll
            for (int ni = 0; ni < 2; ++ni) {
                int n0 = hf * 128 + w * 32 + ni * 16 + g * 4;
                f32x4 b2v = *(const f32x4*)(b2 + n0);
                #pragma unroll
                for (int mi = 0; mi < 4; ++mi) {
                    int m = mi * 16 + l15;
                    int byte = m * 512 + ((n0 * 2) ^ ((m & 7) << 4));
                    uint2 ph = *(const uint2*)(hA + byte);
                    uint2 pl = *(const uint2*)(hA + HA_LO + byte);
                    f32x4 hres;
                    hres[0] = b2f_lo(ph.x) + b2f_lo(pl.x);
                    hres[1] = b2f_hi(ph.x) + b2f_hi(pl.x);
                    hres[2] = b2f_lo(ph.y) + b2f_lo(pl.y);
                    hres[3] = b2f_hi(ph.y) + b2f_hi(pl.y);
                    f32x4 a = acc[hf][ni][mi];
                    float a0 = fmaxf(a[0], 0.f), a1 = fmaxf(a[1], 0.f);
                    float a2 = fmaxf(a[2], 0.f), a3 = fmaxf(a[3], 0.f);
                    unsigned short s0 = f2bf(a0), s1 = f2bf(a1), s2 = f2bf(a2), s3 = f2bf(a3);
                    uint2 wh_, wl_;
                    wh_.x = (unsigned)s0 | ((unsigned)s1 << 16);
                    wh_.y = (unsigned)s2 | ((unsigned)s3 << 16);
                    wl_.x = (unsigned)f2bf(a0 - bf2f(s0)) | ((unsigned)f2bf(a1 - bf2f(s1)) << 16);
                    wl_.y = (unsigned)f2bf(a2 - bf2f(s2)) | ((unsigned)f2bf(a3 - bf2f(s3)) << 16);
                    *(uint2*)(hA + byte) = wh_;
                    *(uint2*)(hA + HA_LO + byte) = wl_;
                    acc[hf][ni][mi] = hres + b2v;      // phase-B accumulator init
                }
            }
        // ---- phase B: acc += act @ W2^T  (kqloop's leading sync publishes act) ----
        kqloop(WBh, WBl, lds, acc, tid, w, l15, g);

        // ---- epilogue B: hnew = acc -> hA ----
        __syncthreads();                 // all phase-B readers done
        #pragma unroll
        for (int hf = 0; hf < 2; ++hf)
            #pragma unroll
            for (int ni = 0; ni < 2; ++ni) {
                int n0 = hf * 128 + w * 32 + ni * 16 + g * 4;
                #pragma unroll
                for (int mi = 0; mi < 4; ++mi) {
                    int m = mi * 16 + l15;
                    int byte = m * 512 + ((n0 * 2) ^ ((m & 7) << 4));
                    f32x4 a = acc[hf][ni][mi];
                    unsigned short s0 = f2bf(a[0]), s1 = f2bf(a[1]),
                                   s2 = f2bf(a[2]), s3 = f2bf(a[3]);
                    uint2 wh_, wl_;
                    wh_.x = (unsigned)s0 | ((unsigned)s1 << 16);
                    wh_.y = (unsigned)s2 | ((unsigned)s3 << 16);
                    wl_.x = (unsigned)f2bf(a[0] - bf2f(s0)) | ((unsigned)f2bf(a[1] - bf2f(s1)) << 16);
                    wl_.y = (unsigned)f2bf(a[2] - bf2f(s2)) | ((unsigned)f2bf(a[3] - bf2f(s3)) << 16);
                    *(uint2*)(hA + byte) = wh_;
                    *(uint2*)(hA + HA_LO + byte) = wl_;
                    acc[hf][ni][mi] = (f32x4){0.f, 0.f, 0.f, 0.f};
                }
            }
        if (s < 3) {
            STfun(lds, Wc, tid);          // leading barrier covers hnew writes
            #pragma unroll
            for (int hf = 0; hf < 2; ++hf)
                #pragma unroll
                for (int ni = 0; ni < 2; ++ni)
                    tvr[hf][ni] = *(const f32x4*)(Tp + hf * 128 + w * 32 + ni * 16 + g * 4);
        }
    }

    // ---- decoder: logits^T = Wd^T @ h^T, k-split across 4 waves ----
    __syncthreads();                     // hnew visible; Wt region free for Dp
    {
        const int rx = (l15 & 7) << 4;
        float* Dp = (float*)(lds + DP_OFF);
        f32x4 dacc[4];
        #pragma unroll
        for (int mi = 0; mi < 4; ++mi) dacc[mi] = (f32x4){0.f, 0.f, 0.f, 0.f};
        #pragma unroll
        for (int kh = 0; kh < 2; ++kh) {
            int k = w * 64 + kh * 32;
            bf16x8 wdh = *(const bf16x8*)(WDh + (size_t)l15 * 256 + k + g * 8);
            bf16x8 wdl = *(const bf16x8*)(WDl + (size_t)l15 * 256 + k + g * 8);
            #pragma unroll
            for (int mi = 0; mi < 4; ++mi) {
                int mbyte = (mi * 16 + l15) * 512 + ((k * 2 + g * 16) ^ rx);
                bf16x8 hh = *(const bf16x8*)(hA + mbyte);
                bf16x8 hl = *(const bf16x8*)(hA + HA_LO + mbyte);
                dacc[mi] = __builtin_amdgcn_mfma_f32_16x16x32_bf16(wdh, hh, dacc[mi], 0, 0, 0);
                dacc[mi] = __builtin_amdgcn_mfma_f32_16x16x32_bf16(wdl, hh, dacc[mi], 0, 0, 0);
                dacc[mi] = __builtin_amdgcn_mfma_f32_16x16x32_bf16(wdh, hl, dacc[mi], 0, 0, 0);
            }
        }
        #pragma unroll
        for (int mi = 0; mi < 4; ++mi)
            #pragma unroll
            for (int q = 0; q < 4; ++q)
                Dp[w * 1024 + (mi * 16 + l15) * 16 + g * 4 + q] = dacc[mi][q];
    }
    __syncthreads();
    {
        float* Dp = (float*)(lds + DP_OFF);
        int m = tid >> 2, a0 = (tid & 3) * 4;
        float4 bdv = *(const float4*)(bd + a0);
        float4 o;
        #pragma unroll
        for (int j = 0; j < 4; ++j) {
            int idx = m * 16 + a0 + j;
            (&o.x)[j] = Dp[idx] + Dp[1024 + idx] + Dp[2048 + idx] + Dp[3072 + idx] + (&bdv.x)[j];
        }
        *(float4*)(out + ((size_t)rowbase + m) * NACT + a0) = o;
    }
}

extern "C" void kernel_launch(void* const* d_in, const int* in_sizes, int n_in,
                              void* d_out, int out_size, void* d_ws, size_t ws_size,
                              hipStream_t stream) {
    const int*   ids = (const int*)d_in[0];
    const float* emb = (const float*)d_in[1];
    const float* W1  = (const float*)d_in[2];
    const float* b1  = (const float*)d_in[3];
    const float* W2  = (const float*)d_in[4];
    const float* b2  = (const float*)d_in[5];
    const float* Wd  = (const float*)d_in[6];
    const float* bd  = (const float*)d_in[7];
    float* out = (float*)d_out;

    char* p = (char*)d_ws;
    unsigned short* WAh = (unsigned short*)p; p += 65536 * 2;
    unsigned short* WAl = (unsigned short*)p; p += 65536 * 2;
    unsigned short* WHh = (unsigned short*)p; p += 65536 * 2;
    unsigned short* WHl = (unsigned short*)p; p += 65536 * 2;
    unsigned short* WBh = (unsigned short*)p; p += 65536 * 2;
    unsigned short* WBl = (unsigned short*)p; p += 65536 * 2;
    unsigned short* WDh = (unsigned short*)p; p += 4096 * 2;
    unsigned short* WDl = (unsigned short*)p; p += 4096 * 2;
    float* Wc = (float*)p;

    prep_k<<<(PREP_N + 255) / 256, 256, 0, stream>>>(W1, W2, Wd, WAh, WAl, WHh, WHl,
                                                     WBh, WBl, WDh, WDl, Wc);
    fused_all<<<NB, 256, 0, stream>>>(ids, emb, WAh, WAl, WHh, WHl, WBh, WBl,
                                      WDh, WDl, Wc, b1, b2, bd, out);
}

// Round 9
// 741.576 us; speedup vs baseline: 1.3807x; 1.3807x over previous
//
#include <hip/hip_runtime.h>

#define HID 256
#define NB 1024
#define NACT 16

typedef __bf16 bf16x8 __attribute__((ext_vector_type(8)));
typedef float  f32x4  __attribute__((ext_vector_type(4)));

// LDS map: hA hi 32K | hA lo 32K | buf0 32K (Wh16+Wl16) | buf1 32K. Total 128 KB.
#define HA_LO   32768
#define BUF0    65536
#define BUF1    98304
#define LDS_TOT 131072
// overlays in BUF0/BUF1 (live only between kqloops):
//   Sp f32[1024]@BUF0 ; Sf f32[256]@BUF0+4096 ; Tp f32[512]@BUF0+8192 ; Dp f32[8192]@BUF0

#define PREP_N (4 * 65536 + 4096)

__device__ __forceinline__ void gload_lds16(const void* g, void* l) {
    __builtin_amdgcn_global_load_lds(
        (const __attribute__((address_space(1))) void*)g,
        (__attribute__((address_space(3))) void*)l, 16, 0, 0);
}
__device__ __forceinline__ unsigned short f2bf(float x) {
    union { __bf16 b; unsigned short u; } v; v.b = (__bf16)x; return v.u;
}
__device__ __forceinline__ float bf2f(unsigned short u) {
    union { unsigned short u; __bf16 b; } v; v.u = u; return (float)v.b;
}
__device__ __forceinline__ float b2f_lo(unsigned v) { return bf2f((unsigned short)(v & 0xffffu)); }
__device__ __forceinline__ float b2f_hi(unsigned v) { return bf2f((unsigned short)(v >> 16)); }

// ---- prep: weights [n][k=256] hi/lo pairs; WD [a=16][k=256]; Wc f32 [k][n] ----
__global__ __launch_bounds__(256) void prep_k(const float* __restrict__ W1,
                                              const float* __restrict__ W2,
                                              const float* __restrict__ Wd,
                                              unsigned short* __restrict__ WAh, unsigned short* __restrict__ WAl,
                                              unsigned short* __restrict__ WHh, unsigned short* __restrict__ WHl,
                                              unsigned short* __restrict__ WBh, unsigned short* __restrict__ WBl,
                                              unsigned short* __restrict__ WDh, unsigned short* __restrict__ WDl,
                                              float* __restrict__ Wc) {
    int i = blockIdx.x * 256 + threadIdx.x;
    const float inv = 1.0f / 63.0f;
    if (i < 65536) {
        int n = i >> 8, k = i & 255;
        float val = W1[k * 256 + n] - inv * W1[(256 + k) * 256 + n];
        unsigned short hi = f2bf(val);
        WAh[i] = hi; WAl[i] = f2bf(val - bf2f(hi));
    } else if (i < 2 * 65536) {
        int j = i - 65536, n = j >> 8, k = j & 255;
        float val = W1[(512 + k) * 256 + n];
        unsigned short hi = f2bf(val);
        WHh[j] = hi; WHl[j] = f2bf(val - bf2f(hi));
    } else if (i < 3 * 65536) {
        int j = i - 2 * 65536, n = j >> 8, k = j & 255;
        float val = W2[k * 256 + n];
        unsigned short hi = f2bf(val);
        WBh[j] = hi; WBl[j] = f2bf(val - bf2f(hi));
    } else if (i < 4 * 65536) {
        int j = i - 3 * 65536, k = j >> 8, n = j & 255;
        Wc[j] = inv * W1[(256 + k) * 256 + n];
    } else if (i < PREP_N) {
        int j = i - 4 * 65536, a = j >> 8, k = j & 255;
        float val = Wd[k * 16 + a];
        unsigned short hi = f2bf(val);
        WDh[j] = hi; WDl[j] = f2bf(val - bf2f(hi));
    }
}

// ---- stage one BK=32 Karatsuba tile pair (Wh 16K + Wl 16K), pre-swizzled src ----
__device__ __forceinline__ void stageW(const unsigned short* __restrict__ Wh,
                                       const unsigned short* __restrict__ Wl,
                                       char* dst, int kq, int tid) {
    #pragma unroll
    for (int p = 0; p < 2; ++p) {
        int c = p * 512 + tid;           // 1024 chunks of 16B per 16KB half
        int n = c >> 2, s = c & 3;
        int sp = s ^ ((n >> 1) & 3);
        gload_lds16(Wh + (size_t)n * 256 + kq * 32 + sp * 8, dst + c * 16);
        gload_lds16(Wl + (size_t)n * 256 + kq * 32 + sp * 8, dst + 16384 + c * 16);
    }
}

// ---- Karatsuba kq-loop: acc[nt][mi] += W·h (3-term split), double-buffered ----
// Roles: MFMA A = W-frag (n), B = h-frag (m). One barrier per kq.
__device__ __forceinline__ void kqloop(const unsigned short* __restrict__ Wh,
                                       const unsigned short* __restrict__ Wl,
                                       char* lds, f32x4 (&acc)[4][2],
                                       int tid, int wq, int whalf, int l15, int g)
{
    char* hA = lds;
    __syncthreads();                     // buf region free; hA writes visible
    stageW(Wh, Wl, lds + BUF0, 0, tid);
    for (int kq = 0; kq < 8; ++kq) {
        __syncthreads();                 // drains vmcnt: tile kq ready; prev readers done
        if (kq < 7)
            stageW(Wh, Wl, lds + ((kq & 1) ? BUF0 : BUF1), kq + 1, tid);
        const char* bufW = lds + ((kq & 1) ? BUF1 : BUF0);
        bf16x8 hfh[2], hfl[2];
        #pragma unroll
        for (int mi = 0; mi < 2; ++mi) {
            int m = whalf * 32 + mi * 16 + l15;
            int byte = m * 512 + ((kq * 64 + g * 16) ^ ((m & 7) << 4));
            hfh[mi] = *(const bf16x8*)(hA + byte);
            hfl[mi] = *(const bf16x8*)(hA + HA_LO + byte);
        }
        #pragma unroll
        for (int nt = 0; nt < 4; ++nt) {
            int n = wq * 64 + nt * 16 + l15;
            int wb = n * 64 + ((g ^ ((n >> 1) & 3)) << 4);
            bf16x8 wfh = *(const bf16x8*)(bufW + wb);
            bf16x8 wfl = *(const bf16x8*)(bufW + 16384 + wb);
            #pragma unroll
            for (int mi = 0; mi < 2; ++mi) {
                acc[nt][mi] = __builtin_amdgcn_mfma_f32_16x16x32_bf16(wfh, hfh[mi], acc[nt][mi], 0, 0, 0);
                acc[nt][mi] = __builtin_amdgcn_mfma_f32_16x16x32_bf16(wfl, hfh[mi], acc[nt][mi], 0, 0, 0);
                acc[nt][mi] = __builtin_amdgcn_mfma_f32_16x16x32_bf16(wfh, hfl[mi], acc[nt][mi], 0, 0, 0);
            }
        }
    }
    // caller must __syncthreads() before writing hA or reusing buf region
}

// ---- S/T: T[n] = (sum_rows h) @ Wc (512 threads; BUF0 overlay) ----
__device__ __forceinline__ void STfun(char* lds, const float* __restrict__ Wc, int tid)
{
    char* hA = lds;
    float* Sp = (float*)(lds + BUF0);
    float* Sf = (float*)(lds + BUF0 + 4096);
    float* Tp = (float*)(lds + BUF0 + 8192);
    __syncthreads();                 // hA writes visible; buf region free
    {
        int ww = tid & 127, gq = tid >> 7;
        float s0 = 0.f, s1 = 0.f;
        #pragma unroll 4
        for (int m = gq * 16; m < gq * 16 + 16; ++m) {
            int byte = m * 512 + ((ww * 4) ^ ((m & 7) << 4));
            unsigned vh = *(const unsigned*)(hA + byte);
            unsigned vl = *(const unsigned*)(hA + HA_LO + byte);
            s0 += b2f_lo(vh) + b2f_lo(vl);
            s1 += b2f_hi(vh) + b2f_hi(vl);
        }
        Sp[gq * 256 + ww * 2] = s0;
        Sp[gq * 256 + ww * 2 + 1] = s1;
    }
    __syncthreads();
    if (tid < 256) Sf[tid] = (Sp[tid] + Sp[256 + tid]) + (Sp[512 + tid] + Sp[768 + tid]);
    __syncthreads();
    {
        int n = tid & 255, kh = tid >> 8;
        float a = 0.f;
        #pragma unroll 8
        for (int k = kh * 128; k < kh * 128 + 128; ++k)
            a += Sf[k] * Wc[(k << 8) + n];
        Tp[kh * 256 + n] = a;
    }
    __syncthreads();                 // Tp visible
}

// ---- whole network, one batch per block (512 threads, 8 waves) ----
__global__ __launch_bounds__(512, 1) void fused_all(
    const int* __restrict__ ids, const float* __restrict__ emb,
    const unsigned short* __restrict__ WAh, const unsigned short* __restrict__ WAl,
    const unsigned short* __restrict__ WHh, const unsigned short* __restrict__ WHl,
    const unsigned short* __restrict__ WBh, const unsigned short* __restrict__ WBl,
    const unsigned short* __restrict__ WDh, const unsigned short* __restrict__ WDl,
    const float* __restrict__ Wc,
    const float* __restrict__ b1, const float* __restrict__ b2,
    const float* __restrict__ bd, float* __restrict__ out)
{
    __shared__ __align__(16) char lds[LDS_TOT];
    const int tid = threadIdx.x;
    const int lane = tid & 63;
    const int w = tid >> 6;
    const int wq = w & 3;                // n-quarter (64 cols)
    const int whalf = w >> 2;            // m-half (32 rows)
    const int l15 = lane & 15, g = lane >> 4;
    const size_t rowbase = (size_t)blockIdx.x * 64;
    char* hA = lds;
    float* Tp = (float*)(lds + BUF0 + 8192);

    // ---- stage h0 = emb[ids] -> split hi/lo, XOR-swizzled (row = lane: conflict-free) ----
    {
        int r = tid & 63;
        int c0 = (tid >> 6) * 32;
        int rx = (r & 7) << 4;
        const float4* src = (const float4*)(emb + (size_t)ids[rowbase + r] * HID + c0);
        char* dh = hA + r * 512;
        char* dl = dh + HA_LO;
        #pragma unroll
        for (int j = 0; j < 8; ++j) {
            float4 v = src[j];
            unsigned short h0 = f2bf(v.x), h1 = f2bf(v.y), h2 = f2bf(v.z), h3 = f2bf(v.w);
            unsigned short q0 = f2bf(v.x - bf2f(h0)), q1 = f2bf(v.y - bf2f(h1)),
                           q2 = f2bf(v.z - bf2f(h2)), q3 = f2bf(v.w - bf2f(h3));
            int byte = ((c0 + j * 4) * 2) ^ rx;
            *(uint2*)(dh + byte) = make_uint2((unsigned)h0 | ((unsigned)h1 << 16),
                                              (unsigned)h2 | ((unsigned)h3 << 16));
            *(uint2*)(dl + byte) = make_uint2((unsigned)q0 | ((unsigned)q1 << 16),
                                              (unsigned)q2 | ((unsigned)q3 << 16));
        }
    }

    STfun(lds, Wc, tid);
    f32x4 tvr[4];
    #pragma unroll
    for (int nt = 0; nt < 4; ++nt) {
        int n0 = wq * 64 + nt * 16 + g * 4;
        tvr[nt] = *(const f32x4*)(Tp + n0) + *(const f32x4*)(Tp + 256 + n0);
    }

    f32x4 acc[4][2], u0r[4][2];
    #pragma unroll
    for (int nt = 0; nt < 4; ++nt)
        #pragma unroll
        for (int mi = 0; mi < 2; ++mi) acc[nt][mi] = (f32x4){0.f, 0.f, 0.f, 0.f};

    for (int s = 0; s < 4; ++s) {
        if (s == 0) {
            // u0 = h0 @ W1h0 + b1  (acc starts 0; hA holds h0)
            kqloop(WHh, WHl, lds, acc, tid, wq, whalf, l15, g);
            #pragma unroll
            for (int nt = 0; nt < 4; ++nt) {
                int n0 = wq * 64 + nt * 16 + g * 4;
                f32x4 b1v = *(const f32x4*)(b1 + n0);
                #pragma unroll
                for (int mi = 0; mi < 2; ++mi) {
                    u0r[nt][mi] = acc[nt][mi] + b1v;
                    acc[nt][mi] = (f32x4){0.f, 0.f, 0.f, 0.f};
                }
            }
        }
        // ---- phase A: acc = T + u0 + h @ Aw ----
        #pragma unroll
        for (int nt = 0; nt < 4; ++nt)
            #pragma unroll
            for (int mi = 0; mi < 2; ++mi)
                acc[nt][mi] = tvr[nt] + u0r[nt][mi];
        kqloop(WAh, WAl, lds, acc, tid, wq, whalf, l15, g);

        // ---- epilogue A: act = relu(acc) -> hA ; acc := hres + b2 ----
        __syncthreads();                 // all phase-A hA/buf readers done
        #pragma unroll
        for (int nt = 0; nt < 4; ++nt) {
            int n0 = wq * 64 + nt * 16 + g * 4;
            f32x4 b2v = *(const f32x4*)(b2 + n0);
            #pragma unroll
            for (int mi = 0; mi < 2; ++mi) {
                int m = whalf * 32 + mi * 16 + l15;
                int byte = m * 512 + ((n0 * 2) ^ ((m & 7) << 4));
                uint2 ph = *(const uint2*)(hA + byte);
                uint2 pl = *(const uint2*)(hA + HA_LO + byte);
                f32x4 hres;
                hres[0] = b2f_lo(ph.x) + b2f_lo(pl.x);
                hres[1] = b2f_hi(ph.x) + b2f_hi(pl.x);
                hres[2] = b2f_lo(ph.y) + b2f_lo(pl.y);
                hres[3] = b2f_hi(ph.y) + b2f_hi(pl.y);
                f32x4 av = acc[nt][mi];
                float a0 = fmaxf(av[0], 0.f), a1 = fmaxf(av[1], 0.f);
                float a2 = fmaxf(av[2], 0.f), a3 = fmaxf(av[3], 0.f);
                unsigned short s0 = f2bf(a0), s1 = f2bf(a1), s2 = f2bf(a2), s3 = f2bf(a3);
                uint2 whv, wlv;
                whv.x = (unsigned)s0 | ((unsigned)s1 << 16);
                whv.y = (unsigned)s2 | ((unsigned)s3 << 16);
                wlv.x = (unsigned)f2bf(a0 - bf2f(s0)) | ((unsigned)f2bf(a1 - bf2f(s1)) << 16);
                wlv.y = (unsigned)f2bf(a2 - bf2f(s2)) | ((unsigned)f2bf(a3 - bf2f(s3)) << 16);
                *(uint2*)(hA + byte) = whv;
                *(uint2*)(hA + HA_LO + byte) = wlv;
                acc[nt][mi] = hres + b2v;        // phase-B accumulator init
            }
        }

        // ---- phase B: acc += act @ W2  (kqloop entry sync publishes act) ----
        kqloop(WBh, WBl, lds, acc, tid, wq, whalf, l15, g);

        // ---- epilogue B: hnew = acc -> hA ----
        __syncthreads();                 // all phase-B readers done
        #pragma unroll
        for (int nt = 0; nt < 4; ++nt) {
            int n0 = wq * 64 + nt * 16 + g * 4;
            #pragma unroll
            for (int mi = 0; mi < 2; ++mi) {
                int m = whalf * 32 + mi * 16 + l15;
                int byte = m * 512 + ((n0 * 2) ^ ((m & 7) << 4));
                f32x4 av = acc[nt][mi];
                unsigned short s0 = f2bf(av[0]), s1 = f2bf(av[1]),
                               s2 = f2bf(av[2]), s3 = f2bf(av[3]);
                uint2 whv, wlv;
                whv.x = (unsigned)s0 | ((unsigned)s1 << 16);
                whv.y = (unsigned)s2 | ((unsigned)s3 << 16);
                wlv.x = (unsigned)f2bf(av[0] - bf2f(s0)) | ((unsigned)f2bf(av[1] - bf2f(s1)) << 16);
                wlv.y = (unsigned)f2bf(av[2] - bf2f(s2)) | ((unsigned)f2bf(av[3] - bf2f(s3)) << 16);
                *(uint2*)(hA + byte) = whv;
                *(uint2*)(hA + HA_LO + byte) = wlv;
                acc[nt][mi] = (f32x4){0.f, 0.f, 0.f, 0.f};
            }
        }

        if (s < 3) {
            STfun(lds, Wc, tid);          // entry sync covers hnew writes
            #pragma unroll
            for (int nt = 0; nt < 4; ++nt) {
                int n0 = wq * 64 + nt * 16 + g * 4;
                tvr[nt] = *(const f32x4*)(Tp + n0) + *(const f32x4*)(Tp + 256 + n0);
            }
        }
    }

    // ---- decoder: logits = h @ Wd + bd (8-way k-split; Wd frags from global/L2) ----
    __syncthreads();                     // hnew visible; buf region free for Dp
    {
        float* Dp = (float*)(lds + BUF0);  // 8 waves x 64 m x 16 a = 32 KB
        f32x4 dacc[4];
        #pragma unroll
        for (int mi = 0; mi < 4; ++mi) dacc[mi] = (f32x4){0.f, 0.f, 0.f, 0.f};
        const int k = w * 32;
        bf16x8 wdh = *(const bf16x8*)(WDh + (size_t)l15 * 256 + k + g * 8);
        bf16x8 wdl = *(const bf16x8*)(WDl + (size_t)l15 * 256 + k + g * 8);
        #pragma unroll
        for (int mi = 0; mi < 4; ++mi) {
            int m = mi * 16 + l15;
            int byte = m * 512 + ((k * 2 + g * 16) ^ ((m & 7) << 4));
            bf16x8 hh = *(const bf16x8*)(hA + byte);
            bf16x8 hl = *(const bf16x8*)(hA + HA_LO + byte);
            dacc[mi] = __builtin_amdgcn_mfma_f32_16x16x32_bf16(wdh, hh, dacc[mi], 0, 0, 0);
            dacc[mi] = __builtin_amdgcn_mfma_f32_16x16x32_bf16(wdl, hh, dacc[mi], 0, 0, 0);
            dacc[mi] = __builtin_amdgcn_mfma_f32_16x16x32_bf16(wdh, hl, dacc[mi], 0, 0, 0);
        }
        #pragma unroll
        for (int mi = 0; mi < 4; ++mi)
            #pragma unroll
            for (int q = 0; q < 4; ++q)
                Dp[w * 1024 + (mi * 16 + l15) * 16 + g * 4 + q] = dacc[mi][q];
    }
    __syncthreads();
    {
        float* Dp = (float*)(lds + BUF0);
        int m = tid >> 3, a0 = (tid & 7) * 2;
        float o0 = bd[a0], o1 = bd[a0 + 1];
        #pragma unroll
        for (int w8 = 0; w8 < 8; ++w8) {
            o0 += Dp[w8 * 1024 + m * 16 + a0];
            o1 += Dp[w8 * 1024 + m * 16 + a0 + 1];
        }
        *(float2*)(out + ((size_t)rowbase + m) * NACT + a0) = make_float2(o0, o1);
    }
}

extern "C" void kernel_launch(void* const* d_in, const int* in_sizes, int n_in,
                              void* d_out, int out_size, void* d_ws, size_t ws_size,
                              hipStream_t stream) {
    const int*   ids = (const int*)d_in[0];
    const float* emb = (const float*)d_in[1];
    const float* W1  = (const float*)d_in[2];
    const float* b1  = (const float*)d_in[3];
    const float* W2  = (const float*)d_in[4];
    const float* b2  = (const float*)d_in[5];
    const float* Wd  = (const float*)d_in[6];
    const float* bd  = (const float*)d_in[7];
    float* out = (float*)d_out;

    char* p = (char*)d_ws;
    unsigned short* WAh = (unsigned short*)p; p += 65536 * 2;
    unsigned short* WAl = (unsigned short*)p; p += 65536 * 2;
    unsigned short* WHh = (unsigned short*)p; p += 65536 * 2;
    unsigned short* WHl = (unsigned short*)p; p += 65536 * 2;
    unsigned short* WBh = (unsigned short*)p; p += 65536 * 2;
    unsigned short* WBl = (unsigned short*)p; p += 65536 * 2;
    unsigned short* WDh = (unsigned short*)p; p += 4096 * 2;
    unsigned short* WDl = (unsigned short*)p; p += 4096 * 2;
    float* Wc = (float*)p;

    prep_k<<<(PREP_N + 255) / 256, 256, 0, stream>>>(W1, W2, Wd, WAh, WAl, WHh, WHl,
                                                     WBh, WBl, WDh, WDl, Wc);
    fused_all<<<NB, 512, 0, stream>>>(ids, emb, WAh, WAl, WHh, WHl, WBh, WBl,
                                      WDh, WDl, Wc, b1, b2, bd, out);
}

// Round 10
// 327.736 us; speedup vs baseline: 3.1241x; 2.2627x over previous
//
#include <hip/hip_runtime.h>

#define HID 256
#define NB 1024
#define NACT 16

typedef __bf16 bf16x8 __attribute__((ext_vector_type(8)));
typedef float  f32x4  __attribute__((ext_vector_type(4)));

// LDS map: hA hi 32K | hA lo 32K | BUF0 32K (Wh16+Wl16) | BUF1 32K. Total 128 KB.
#define HA_LO   32768
#define BUF0    65536
#define BUF1    98304
#define LDS_TOT 131072
// overlays in BUF0 (live only between kqloops):
//   Sp f32[1024]@BUF0 ; Sf f32[256]@+4096 ; Tp f32[512]@+8192 ; Dp f32[8192]@BUF0

#define PREP_N (4 * 65536 + 4096)

__device__ __forceinline__ void gload_lds16(const void* g, void* l) {
    __builtin_amdgcn_global_load_lds(
        (const __attribute__((address_space(1))) void*)g,
        (__attribute__((address_space(3))) void*)l, 16, 0, 0);
}
__device__ __forceinline__ unsigned short f2bf(float x) {
    union { float f; unsigned u; } v; v.f = x;
    unsigned r = v.u + 0x7fff + ((v.u >> 16) & 1);
    return (unsigned short)(r >> 16);
}
__device__ __forceinline__ float bf2f(unsigned short b) {
    union { float f; unsigned u; } v; v.u = ((unsigned)b) << 16;
    return v.f;
}
__device__ __forceinline__ float b2f_lo(unsigned v) { return bf2f((unsigned short)(v & 0xffffu)); }
__device__ __forceinline__ float b2f_hi(unsigned v) { return bf2f((unsigned short)(v >> 16)); }

// ---- prep: weights [n][k=256] hi/lo pairs; WD [a=16][k=256] pairs; Wc f32 [k][n] ----
__global__ __launch_bounds__(256) void prep_k(const float* __restrict__ W1,
                                              const float* __restrict__ W2,
                                              const float* __restrict__ Wd,
                                              unsigned short* __restrict__ WAh, unsigned short* __restrict__ WAl,
                                              unsigned short* __restrict__ WHh, unsigned short* __restrict__ WHl,
                                              unsigned short* __restrict__ WBh, unsigned short* __restrict__ WBl,
                                              unsigned short* __restrict__ WDh, unsigned short* __restrict__ WDl,
                                              float* __restrict__ Wc) {
    int i = blockIdx.x * 256 + threadIdx.x;
    const float inv = 1.0f / 63.0f;
    if (i < 65536) {
        int n = i >> 8, k = i & 255;
        float val = W1[k * 256 + n] - inv * W1[(256 + k) * 256 + n];
        unsigned short hi = f2bf(val);
        WAh[i] = hi; WAl[i] = f2bf(val - bf2f(hi));
    } else if (i < 2 * 65536) {
        int j = i - 65536, n = j >> 8, k = j & 255;
        float val = W1[(512 + k) * 256 + n];
        unsigned short hi = f2bf(val);
        WHh[j] = hi; WHl[j] = f2bf(val - bf2f(hi));
    } else if (i < 3 * 65536) {
        int j = i - 2 * 65536, n = j >> 8, k = j & 255;
        float val = W2[k * 256 + n];
        unsigned short hi = f2bf(val);
        WBh[j] = hi; WBl[j] = f2bf(val - bf2f(hi));
    } else if (i < 4 * 65536) {
        int j = i - 3 * 65536, k = j >> 8, n = j & 255;
        Wc[j] = inv * W1[(256 + k) * 256 + n];
    } else if (i < PREP_N) {
        int j = i - 4 * 65536, a = j >> 8, k = j & 255;
        float val = Wd[k * 16 + a];
        unsigned short hi = f2bf(val);
        WDh[j] = hi; WDl[j] = f2bf(val - bf2f(hi));
    }
}

// ---- Karatsuba kq-loop (round-7 skeleton): acc[mi][nt] += h@W (3-term split) ----
// Weight tile pair per kq: Wh [256n][32k] + Wl, 32 KB, double-buffered.
__device__ __forceinline__ void kloopKar(const unsigned short* __restrict__ Wh,
                                         const unsigned short* __restrict__ Wl,
                                         char* lds, f32x4 (&acc)[2][4],
                                         int tid, int wm, int wn, int l15, int g)
{
    char* hA = lds;
    const int rxA = (l15 & 7) << 4;
    const int rowA0 = (wm * 32 + l15) * 512;
    const int rowA1 = rowA0 + 16 * 512;

    __syncthreads();                       // buf region free; prior hA writes visible
    #pragma unroll
    for (int p = 0; p < 2; ++p) {          // stage kq=0 -> BUF0
        int c = p * 512 + tid;
        int n = c >> 2, s = c & 3;
        int sp = s ^ ((n >> 1) & 3);
        gload_lds16(Wh + (size_t)n * 256 + sp * 8, lds + BUF0 + c * 16);
        gload_lds16(Wl + (size_t)n * 256 + sp * 8, lds + BUF0 + 16384 + c * 16);
    }
    __syncthreads();                       // buf0 ready (barrier drains vmcnt)

    #pragma unroll 2
    for (int kq = 0; kq < 8; ++kq) {
        const int cur = kq & 1;
        if (kq + 1 < 8) {                  // issue next tile BEFORE compute
            const int kk = (kq + 1) * 32;
            char* dst = lds + (cur ? BUF0 : BUF1);
            #pragma unroll
            for (int p = 0; p < 2; ++p) {
                int c = p * 512 + tid;
                int n = c >> 2, s = c & 3;
                int sp = s ^ ((n >> 1) & 3);
                gload_lds16(Wh + (size_t)n * 256 + kk + sp * 8, dst + c * 16);
                gload_lds16(Wl + (size_t)n * 256 + kk + sp * 8, dst + 16384 + c * 16);
            }
        }
        const char* bb = lds + (cur ? BUF1 : BUF0);
        const int cb = (kq * 64 + g * 16) ^ rxA;
        bf16x8 a0h = *(const bf16x8*)(hA + rowA0 + cb);
        bf16x8 a1h = *(const bf16x8*)(hA + rowA1 + cb);
        bf16x8 a0l = *(const bf16x8*)(hA + HA_LO + rowA0 + cb);
        bf16x8 a1l = *(const bf16x8*)(hA + HA_LO + rowA1 + cb);
        #pragma unroll
        for (int nt = 0; nt < 4; ++nt) {
            int nn = wn * 64 + nt * 16 + l15;
            int off = nn * 64 + ((g ^ ((nn >> 1) & 3)) << 4);
            bf16x8 bh = *(const bf16x8*)(bb + off);
            bf16x8 bl = *(const bf16x8*)(bb + 16384 + off);
            acc[0][nt] = __builtin_amdgcn_mfma_f32_16x16x32_bf16(a0h, bh, acc[0][nt], 0, 0, 0);
            acc[1][nt] = __builtin_amdgcn_mfma_f32_16x16x32_bf16(a1h, bh, acc[1][nt], 0, 0, 0);
            acc[0][nt] = __builtin_amdgcn_mfma_f32_16x16x32_bf16(a0l, bh, acc[0][nt], 0, 0, 0);
            acc[1][nt] = __builtin_amdgcn_mfma_f32_16x16x32_bf16(a1l, bh, acc[1][nt], 0, 0, 0);
            acc[0][nt] = __builtin_amdgcn_mfma_f32_16x16x32_bf16(a0h, bl, acc[0][nt], 0, 0, 0);
            acc[1][nt] = __builtin_amdgcn_mfma_f32_16x16x32_bf16(a1h, bl, acc[1][nt], 0, 0, 0);
        }
        __syncthreads();                   // drains kq+1 loads; bb readers done
    }
}

// ---- S/T: T[n] = (sum_rows h) @ Wc (512 threads; BUF0 overlay) ----
__device__ __forceinline__ void STfun(char* lds, const float* __restrict__ Wc, int tid)
{
    char* hA = lds;
    float* Sp = (float*)(lds + BUF0);
    float* Sf = (float*)(lds + BUF0 + 4096);
    float* Tp = (float*)(lds + BUF0 + 8192);
    __syncthreads();                 // hA writes visible; buf region free
    {
        int ww = tid & 127, gq = tid >> 7;
        float s0 = 0.f, s1 = 0.f;
        #pragma unroll 4
        for (int m = gq * 16; m < gq * 16 + 16; ++m) {
            int byte = m * 512 + ((ww * 4) ^ ((m & 7) << 4));
            unsigned vh = *(const unsigned*)(hA + byte);
            unsigned vl = *(const unsigned*)(hA + HA_LO + byte);
            s0 += b2f_lo(vh) + b2f_lo(vl);
            s1 += b2f_hi(vh) + b2f_hi(vl);
        }
        Sp[gq * 256 + ww * 2] = s0;
        Sp[gq * 256 + ww * 2 + 1] = s1;
    }
    __syncthreads();
    if (tid < 256) Sf[tid] = (Sp[tid] + Sp[256 + tid]) + (Sp[512 + tid] + Sp[768 + tid]);
    __syncthreads();
    {
        int n = tid & 255, kh = tid >> 8;
        float a = 0.f;
        #pragma unroll 8
        for (int k = kh * 128; k < kh * 128 + 128; ++k)
            a += Sf[k] * Wc[(k << 8) + n];
        Tp[kh * 256 + n] = a;
    }
    __syncthreads();                 // Tp visible
}

// ---- whole network, one batch per block (512 threads, 8 waves) ----
__global__ __launch_bounds__(512, 2) void fused_all(
    const int* __restrict__ ids, const float* __restrict__ emb,
    const unsigned short* __restrict__ WAh, const unsigned short* __restrict__ WAl,
    const unsigned short* __restrict__ WHh, const unsigned short* __restrict__ WHl,
    const unsigned short* __restrict__ WBh, const unsigned short* __restrict__ WBl,
    const unsigned short* __restrict__ WDh, const unsigned short* __restrict__ WDl,
    const float* __restrict__ Wc,
    const float* __restrict__ b1, const float* __restrict__ b2,
    const float* __restrict__ bd, float* __restrict__ out)
{
    __shared__ __align__(16) char lds[LDS_TOT];
    const int tid = threadIdx.x;
    const int lane = tid & 63;
    const int w = tid >> 6;
    const int wm = w >> 2, wn = w & 3;     // m-half, n-quarter (round-7 mapping)
    const int l15 = lane & 15, g = lane >> 4;
    const size_t rowbase = (size_t)blockIdx.x * 64;
    char* hA = lds;
    float* Tp = (float*)(lds + BUF0 + 8192);

    // ---- stage h0 = emb[ids] -> split hi/lo, XOR-swizzled (round-7 verbatim) ----
    {
        int r = tid >> 3, c0 = (tid & 7) * 32;
        int rx = (r & 7) << 4;
        const float4* src = (const float4*)(emb + (size_t)ids[rowbase + r] * HID + c0);
        char* dh = hA + r * 512;
        #pragma unroll
        for (int j = 0; j < 8; ++j) {
            float4 v = src[j];
            unsigned short h0 = f2bf(v.x), h1 = f2bf(v.y), h2 = f2bf(v.z), h3 = f2bf(v.w);
            unsigned short q0 = f2bf(v.x - bf2f(h0)), q1 = f2bf(v.y - bf2f(h1)),
                           q2 = f2bf(v.z - bf2f(h2)), q3 = f2bf(v.w - bf2f(h3));
            int byte = ((c0 + j * 4) * 2) ^ rx;
            *(uint2*)(dh + byte) = make_uint2((unsigned)h0 | ((unsigned)h1 << 16),
                                             (unsigned)h2 | ((unsigned)h3 << 16));
            *(uint2*)(dh + HA_LO + byte) = make_uint2((unsigned)q0 | ((unsigned)q1 << 16),
                                                      (unsigned)q2 | ((unsigned)q3 << 16));
        }
    }

    // per-thread b2 regs (b1 loaded once in s==0 path)
    float b2r[4];
    #pragma unroll
    for (int nt = 0; nt < 4; ++nt) b2r[nt] = b2[wn * 64 + nt * 16 + l15];

    STfun(lds, Wc, tid);
    float tvr[4];
    #pragma unroll
    for (int nt = 0; nt < 4; ++nt) {
        int col = wn * 64 + nt * 16 + l15;
        tvr[nt] = Tp[col] + Tp[256 + col];
    }

    f32x4 acc[2][4], u0r[2][4];
    #pragma unroll
    for (int mt = 0; mt < 2; ++mt)
        #pragma unroll
        for (int nt = 0; nt < 4; ++nt) acc[mt][nt] = (f32x4){0.f, 0.f, 0.f, 0.f};

    for (int s = 0; s < 4; ++s) {
        if (s == 0) {
            // u0 = h0 @ W1h0 + b1 (acc starts 0; hA holds h0)
            kloopKar(WHh, WHl, lds, acc, tid, wm, wn, l15, g);
            #pragma unroll
            for (int nt = 0; nt < 4; ++nt) {
                float bb = b1[wn * 64 + nt * 16 + l15];
                #pragma unroll
                for (int mt = 0; mt < 2; ++mt)
                    #pragma unroll
                    for (int q = 0; q < 4; ++q) {
                        u0r[mt][nt][q] = acc[mt][nt][q] + bb;
                        acc[mt][nt][q] = 0.f;
                    }
            }
        }
        // ---- phase A: acc = T + u0, then acc += h @ Aw ----
        #pragma unroll
        for (int mt = 0; mt < 2; ++mt)
            #pragma unroll
            for (int nt = 0; nt < 4; ++nt)
                #pragma unroll
                for (int q = 0; q < 4; ++q)
                    acc[mt][nt][q] = tvr[nt] + u0r[mt][nt][q];
        kloopKar(WAh, WAl, lds, acc, tid, wm, wn, l15, g);

        // ---- epilogue A: act = relu(acc) -> hA ; acc := hres + b2 (round-7 verbatim) ----
        #pragma unroll
        for (int mt = 0; mt < 2; ++mt)
            #pragma unroll
            for (int nt = 0; nt < 4; ++nt)
                #pragma unroll
                for (int q = 0; q < 4; ++q) {
                    int row = wm * 32 + mt * 16 + g * 4 + q;
                    int col = wn * 64 + nt * 16 + l15;
                    int byte = row * 512 + ((col * 2) ^ ((row & 7) << 4));
                    float hres = bf2f(*(const unsigned short*)(hA + byte))
                               + bf2f(*(const unsigned short*)(hA + HA_LO + byte));
                    float a = fmaxf(acc[mt][nt][q], 0.f);
                    unsigned short hi = f2bf(a);
                    *(unsigned short*)(hA + byte) = hi;
                    *(unsigned short*)(hA + HA_LO + byte) = f2bf(a - bf2f(hi));
                    acc[mt][nt][q] = hres + b2r[nt];
                }

        // ---- phase B: acc += act @ W2 (kloop entry sync publishes act) ----
        kloopKar(WBh, WBl, lds, acc, tid, wm, wn, l15, g);

        // ---- epilogue B: hnew = acc -> hA ----
        #pragma unroll
        for (int mt = 0; mt < 2; ++mt)
            #pragma unroll
            for (int nt = 0; nt < 4; ++nt)
                #pragma unroll
                for (int q = 0; q < 4; ++q) {
                    int row = wm * 32 + mt * 16 + g * 4 + q;
                    int col = wn * 64 + nt * 16 + l15;
                    int byte = row * 512 + ((col * 2) ^ ((row & 7) << 4));
                    float hv = acc[mt][nt][q];
                    unsigned short hi = f2bf(hv);
                    *(unsigned short*)(hA + byte) = hi;
                    *(unsigned short*)(hA + HA_LO + byte) = f2bf(hv - bf2f(hi));
                    acc[mt][nt][q] = 0.f;
                }

        if (s < 3) {
            STfun(lds, Wc, tid);          // entry sync covers hnew writes
            #pragma unroll
            for (int nt = 0; nt < 4; ++nt) {
                int col = wn * 64 + nt * 16 + l15;
                tvr[nt] = Tp[col] + Tp[256 + col];
            }
        }
    }

    // ---- decoder: logits = h @ Wd + bd (8-way k-split; round-9 proven mapping) ----
    __syncthreads();                     // hnew visible; buf region free for Dp
    {
        float* Dp = (float*)(lds + BUF0);  // 8 waves x 64 m x 16 a = 32 KB
        f32x4 dacc[4];
        #pragma unroll
        for (int mi = 0; mi < 4; ++mi) dacc[mi] = (f32x4){0.f, 0.f, 0.f, 0.f};
        const int k = w * 32;
        bf16x8 wdh = *(const bf16x8*)(WDh + (size_t)l15 * 256 + k + g * 8);
        bf16x8 wdl = *(const bf16x8*)(WDl + (size_t)l15 * 256 + k + g * 8);
        #pragma unroll
        for (int mi = 0; mi < 4; ++mi) {
            int m = mi * 16 + l15;
            int byte = m * 512 + ((k * 2 + g * 16) ^ ((m & 7) << 4));
            bf16x8 hh = *(const bf16x8*)(hA + byte);
            bf16x8 hl = *(const bf16x8*)(hA + HA_LO + byte);
            dacc[mi] = __builtin_amdgcn_mfma_f32_16x16x32_bf16(wdh, hh, dacc[mi], 0, 0, 0);
            dacc[mi] = __builtin_amdgcn_mfma_f32_16x16x32_bf16(wdl, hh, dacc[mi], 0, 0, 0);
            dacc[mi] = __builtin_amdgcn_mfma_f32_16x16x32_bf16(wdh, hl, dacc[mi], 0, 0, 0);
        }
        #pragma unroll
        for (int mi = 0; mi < 4; ++mi)
            #pragma unroll
            for (int q = 0; q < 4; ++q)
                Dp[w * 1024 + (mi * 16 + l15) * 16 + g * 4 + q] = dacc[mi][q];
    }
    __syncthreads();
    {
        float* Dp = (float*)(lds + BUF0);
        int m = tid >> 3, a0 = (tid & 7) * 2;
        float o0 = bd[a0], o1 = bd[a0 + 1];
        #pragma unroll
        for (int w8 = 0; w8 < 8; ++w8) {
            o0 += Dp[w8 * 1024 + m * 16 + a0];
            o1 += Dp[w8 * 1024 + m * 16 + a0 + 1];
        }
        *(float2*)(out + ((size_t)rowbase + m) * NACT + a0) = make_float2(o0, o1);
    }
}

extern "C" void kernel_launch(void* const* d_in, const int* in_sizes, int n_in,
                              void* d_out, int out_size, void* d_ws, size_t ws_size,
                              hipStream_t stream) {
    const int*   ids = (const int*)d_in[0];
    const float* emb = (const float*)d_in[1];
    const float* W1  = (const float*)d_in[2];
    const float* b1  = (const float*)d_in[3];
    const float* W2  = (const float*)d_in[4];
    const float* b2  = (const float*)d_in[5];
    const float* Wd  = (const float*)d_in[6];
    const float* bd  = (const float*)d_in[7];
    float* out = (float*)d_out;

    char* p = (char*)d_ws;
    unsigned short* WAh = (unsigned short*)p; p += 65536 * 2;
    unsigned short* WAl = (unsigned short*)p; p += 65536 * 2;
    unsigned short* WHh = (unsigned short*)p; p += 65536 * 2;
    unsigned short* WHl = (unsigned short*)p; p += 65536 * 2;
    unsigned short* WBh = (unsigned short*)p; p += 65536 * 2;
    unsigned short* WBl = (unsigned short*)p; p += 65536 * 2;
    unsigned short* WDh = (unsigned short*)p; p += 4096 * 2;
    unsigned short* WDl = (unsigned short*)p; p += 4096 * 2;
    float* Wc = (float*)p;

    prep_k<<<(PREP_N + 255) / 256, 256, 0, stream>>>(W1, W2, Wd, WAh, WAl, WHh, WHl,
                                                     WBh, WBl, WDh, WDl, Wc);
    fused_all<<<NB, 512, 0, stream>>>(ids, emb, WAh, WAl, WHh, WHl, WBh, WBl,
                                      WDh, WDl, Wc, b1, b2, bd, out);
}

// Round 11
// 273.425 us; speedup vs baseline: 3.7446x; 1.1986x over previous
//
#include <hip/hip_runtime.h>

#define HID 256
#define NB 1024
#define NACT 16

typedef __bf16 bf16x8 __attribute__((ext_vector_type(8)));
typedef float  f32x4  __attribute__((ext_vector_type(4)));

// LDS: hA hi 32K | hA lo 32K | overlay 16K (Sp/Sf/Tp between steps, Dp in decoder)
#define HA_LO   32768
#define OV      65536
#define LDS_TOT 81920

#define PREP_N (4 * 65536 + 4096)

__device__ __forceinline__ unsigned short f2bf(float x) {
    union { float f; unsigned u; } v; v.f = x;
    unsigned r = v.u + 0x7fff + ((v.u >> 16) & 1);
    return (unsigned short)(r >> 16);
}
__device__ __forceinline__ float bf2f(unsigned short b) {
    union { float f; unsigned u; } v; v.u = ((unsigned)b) << 16;
    return v.f;
}
__device__ __forceinline__ float b2f_lo(unsigned v) { return bf2f((unsigned short)(v & 0xffffu)); }
__device__ __forceinline__ float b2f_hi(unsigned v) { return bf2f((unsigned short)(v >> 16)); }

// ---- prep: WA/WH/WB in MFMA FRAGMENT ORDER [kq][nb][lane][8] (hi/lo pairs);
//      WD [a=16][k=256] pairs; Wc f32 [k][n] ----
// frag element: n = nb*16 + (lane&15), k = kq*32 + (lane>>4)*8 + e
__global__ __launch_bounds__(256) void prep_k(const float* __restrict__ W1,
                                              const float* __restrict__ W2,
                                              const float* __restrict__ Wd,
                                              unsigned short* __restrict__ WAh, unsigned short* __restrict__ WAl,
                                              unsigned short* __restrict__ WHh, unsigned short* __restrict__ WHl,
                                              unsigned short* __restrict__ WBh, unsigned short* __restrict__ WBl,
                                              unsigned short* __restrict__ WDh, unsigned short* __restrict__ WDl,
                                              float* __restrict__ Wc) {
    int i = blockIdx.x * 256 + threadIdx.x;
    const float inv = 1.0f / 63.0f;
    if (i < 3 * 65536) {
        int mat = i >> 16, j = i & 65535;
        int kq = j >> 13, r = j & 8191;
        int nb = r >> 9, r2 = r & 511;
        int l = r2 >> 3, e = r2 & 7;
        int n = nb * 16 + (l & 15);
        int k = kq * 32 + (l >> 4) * 8 + e;
        float val;
        if (mat == 0)      val = W1[k * 256 + n] - inv * W1[(256 + k) * 256 + n];
        else if (mat == 1) val = W1[(512 + k) * 256 + n];
        else               val = W2[k * 256 + n];
        unsigned short hi = f2bf(val);
        unsigned short lo = f2bf(val - bf2f(hi));
        if (mat == 0)      { WAh[j] = hi; WAl[j] = lo; }
        else if (mat == 1) { WHh[j] = hi; WHl[j] = lo; }
        else               { WBh[j] = hi; WBl[j] = lo; }
    } else if (i < 4 * 65536) {
        int j = i - 3 * 65536, k = j >> 8, n = j & 255;
        Wc[j] = inv * W1[(256 + k) * 256 + n];
    } else if (i < PREP_N) {
        int j = i - 4 * 65536, a = j >> 8, k = j & 255;
        float val = Wd[k * 16 + a];
        unsigned short hi = f2bf(val);
        WDh[j] = hi; WDl[j] = f2bf(val - bf2f(hi));
    }
}

// ---- barrier-free Karatsuba K-loop: B-frags straight from L2 (frag order) ----
// Wave w owns all 64 m-rows x cols [w*32, w*32+32). acc[mt 4][nt 2].
__device__ __forceinline__ void kloopL2(const unsigned short* __restrict__ Wfh,
                                        const unsigned short* __restrict__ Wfl,
                                        const char* hA, f32x4 (&acc)[4][2],
                                        int w, int lane, int l15, int g)
{
    const int rxA = (l15 & 7) << 4;
    const size_t lbase = ((size_t)(w * 2) * 64 + lane) * 8;   // shorts
    #pragma unroll 2
    for (int kq = 0; kq < 8; ++kq) {
        const int cb = (kq * 64 + g * 16) ^ rxA;
        bf16x8 ah[4], al[4];
        #pragma unroll
        for (int mt = 0; mt < 4; ++mt) {
            int rb = (mt * 16 + l15) * 512;
            ah[mt] = *(const bf16x8*)(hA + rb + cb);
            al[mt] = *(const bf16x8*)(hA + HA_LO + rb + cb);
        }
        const size_t kb = (size_t)kq * 8192 + lbase;
        #pragma unroll
        for (int nt = 0; nt < 2; ++nt) {
            bf16x8 bh = *(const bf16x8*)(Wfh + kb + nt * 512);
            bf16x8 bl = *(const bf16x8*)(Wfl + kb + nt * 512);
            #pragma unroll
            for (int mt = 0; mt < 4; ++mt) {
                acc[mt][nt] = __builtin_amdgcn_mfma_f32_16x16x32_bf16(ah[mt], bh, acc[mt][nt], 0, 0, 0);
                acc[mt][nt] = __builtin_amdgcn_mfma_f32_16x16x32_bf16(al[mt], bh, acc[mt][nt], 0, 0, 0);
                acc[mt][nt] = __builtin_amdgcn_mfma_f32_16x16x32_bf16(ah[mt], bl, acc[mt][nt], 0, 0, 0);
            }
        }
    }
}

// ---- S/T: T[n] = (sum_rows h) @ Wc (512 threads; overlay region) ----
__device__ __forceinline__ void STfun(char* lds, const float* __restrict__ Wc, int tid)
{
    char* hA = lds;
    float* Sp = (float*)(lds + OV);
    float* Sf = (float*)(lds + OV + 4096);
    float* Tp = (float*)(lds + OV + 8192);
    __syncthreads();                 // hA writes visible; overlay free
    {
        int ww = tid & 127, gq = tid >> 7;
        float s0 = 0.f, s1 = 0.f;
        #pragma unroll 4
        for (int m = gq * 16; m < gq * 16 + 16; ++m) {
            int byte = m * 512 + ((ww * 4) ^ ((m & 7) << 4));
            unsigned vh = *(const unsigned*)(hA + byte);
            unsigned vl = *(const unsigned*)(hA + HA_LO + byte);
            s0 += b2f_lo(vh) + b2f_lo(vl);
            s1 += b2f_hi(vh) + b2f_hi(vl);
        }
        Sp[gq * 256 + ww * 2] = s0;
        Sp[gq * 256 + ww * 2 + 1] = s1;
    }
    __syncthreads();
    if (tid < 256) Sf[tid] = (Sp[tid] + Sp[256 + tid]) + (Sp[512 + tid] + Sp[768 + tid]);
    __syncthreads();
    {
        int n = tid & 255, kh = tid >> 8;
        float a = 0.f;
        #pragma unroll 8
        for (int k = kh * 128; k < kh * 128 + 128; ++k)
            a += Sf[k] * Wc[(k << 8) + n];
        Tp[kh * 256 + n] = a;
    }
    __syncthreads();                 // Tp visible
}

// ---- whole network, one batch per block (512 threads, 8 waves, 2 blocks/CU) ----
__global__ __launch_bounds__(512, 2) void fused_all(
    const int* __restrict__ ids, const float* __restrict__ emb,
    const unsigned short* __restrict__ WAh, const unsigned short* __restrict__ WAl,
    const unsigned short* __restrict__ WHh, const unsigned short* __restrict__ WHl,
    const unsigned short* __restrict__ WBh, const unsigned short* __restrict__ WBl,
    const unsigned short* __restrict__ WDh, const unsigned short* __restrict__ WDl,
    const float* __restrict__ Wc,
    const float* __restrict__ b1, const float* __restrict__ b2,
    const float* __restrict__ bd, float* __restrict__ out)
{
    __shared__ __align__(16) char lds[LDS_TOT];
    const int tid = threadIdx.x;
    const int lane = tid & 63;
    const int w = tid >> 6;              // wave owns cols [w*32, w*32+32)
    const int l15 = lane & 15, g = lane >> 4;
    const size_t rowbase = (size_t)blockIdx.x * 64;
    char* hA = lds;
    float* Tp = (float*)(lds + OV + 8192);

    // ---- stage h0 = emb[ids] -> split hi/lo, XOR-swizzled ----
    {
        int r = tid >> 3, c0 = (tid & 7) * 32;
        int rx = (r & 7) << 4;
        const float4* src = (const float4*)(emb + (size_t)ids[rowbase + r] * HID + c0);
        char* dh = hA + r * 512;
        #pragma unroll
        for (int j = 0; j < 8; ++j) {
            float4 v = src[j];
            unsigned short h0 = f2bf(v.x), h1 = f2bf(v.y), h2 = f2bf(v.z), h3 = f2bf(v.w);
            unsigned short q0 = f2bf(v.x - bf2f(h0)), q1 = f2bf(v.y - bf2f(h1)),
                           q2 = f2bf(v.z - bf2f(h2)), q3 = f2bf(v.w - bf2f(h3));
            int byte = ((c0 + j * 4) * 2) ^ rx;
            *(uint2*)(dh + byte) = make_uint2((unsigned)h0 | ((unsigned)h1 << 16),
                                             (unsigned)h2 | ((unsigned)h3 << 16));
            *(uint2*)(dh + HA_LO + byte) = make_uint2((unsigned)q0 | ((unsigned)q1 << 16),
                                                      (unsigned)q2 | ((unsigned)q3 << 16));
        }
    }

    STfun(lds, Wc, tid);                 // entry barrier covers h0 staging
    float tvr[2];
    #pragma unroll
    for (int nt = 0; nt < 2; ++nt) {
        int col = w * 32 + nt * 16 + l15;
        tvr[nt] = Tp[col] + Tp[256 + col];
    }

    f32x4 acc[4][2], u0r[4][2];
    #pragma unroll
    for (int mt = 0; mt < 4; ++mt)
        #pragma unroll
        for (int nt = 0; nt < 2; ++nt) acc[mt][nt] = (f32x4){0.f, 0.f, 0.f, 0.f};

    for (int s = 0; s < 4; ++s) {
        if (s == 0) {
            // u0 = h0 @ W1h0 + b1  (acc starts 0; hA holds h0; no hA writes since ST)
            kloopL2(WHh, WHl, hA, acc, w, lane, l15, g);
            #pragma unroll
            for (int nt = 0; nt < 2; ++nt) {
                float bb = b1[w * 32 + nt * 16 + l15];
                #pragma unroll
                for (int mt = 0; mt < 4; ++mt)
                    #pragma unroll
                    for (int q = 0; q < 4; ++q) {
                        u0r[mt][nt][q] = acc[mt][nt][q] + bb;
                        acc[mt][nt][q] = 0.f;
                    }
            }
        }
        // ---- phase A: acc = T + u0, then acc += h @ Aw ----
        #pragma unroll
        for (int mt = 0; mt < 4; ++mt)
            #pragma unroll
            for (int nt = 0; nt < 2; ++nt)
                #pragma unroll
                for (int q = 0; q < 4; ++q)
                    acc[mt][nt][q] = tvr[nt] + u0r[mt][nt][q];
        kloopL2(WAh, WAl, hA, acc, w, lane, l15, g);

        // ---- epilogue A: act = relu(acc) -> hA ; acc := hres + b2 ----
        __syncthreads();                 // all phase-A hA reads done
        {
            float b2r0 = b2[w * 32 + l15], b2r1 = b2[w * 32 + 16 + l15];
            #pragma unroll
            for (int mt = 0; mt < 4; ++mt)
                #pragma unroll
                for (int nt = 0; nt < 2; ++nt)
                    #pragma unroll
                    for (int q = 0; q < 4; ++q) {
                        int row = mt * 16 + g * 4 + q;
                        int col = w * 32 + nt * 16 + l15;
                        int byte = row * 512 + ((col * 2) ^ ((row & 7) << 4));
                        float hres = bf2f(*(const unsigned short*)(hA + byte))
                                   + bf2f(*(const unsigned short*)(hA + HA_LO + byte));
                        float a = fmaxf(acc[mt][nt][q], 0.f);
                        unsigned short hi = f2bf(a);
                        *(unsigned short*)(hA + byte) = hi;
                        *(unsigned short*)(hA + HA_LO + byte) = f2bf(a - bf2f(hi));
                        acc[mt][nt][q] = hres + (nt ? b2r1 : b2r0);
                    }
        }
        __syncthreads();                 // act visible

        // ---- phase B: acc += act @ W2 ----
        kloopL2(WBh, WBl, hA, acc, w, lane, l15, g);

        // ---- epilogue B: hnew = acc -> hA ----
        __syncthreads();                 // all phase-B reads done
        #pragma unroll
        for (int mt = 0; mt < 4; ++mt)
            #pragma unroll
            for (int nt = 0; nt < 2; ++nt)
                #pragma unroll
                for (int q = 0; q < 4; ++q) {
                    int row = mt * 16 + g * 4 + q;
                    int col = w * 32 + nt * 16 + l15;
                    int byte = row * 512 + ((col * 2) ^ ((row & 7) << 4));
                    float hv = acc[mt][nt][q];
                    unsigned short hi = f2bf(hv);
                    *(unsigned short*)(hA + byte) = hi;
                    *(unsigned short*)(hA + HA_LO + byte) = f2bf(hv - bf2f(hi));
                    acc[mt][nt][q] = 0.f;
                }

        if (s < 3) {
            STfun(lds, Wc, tid);          // entry barrier covers hnew writes
            #pragma unroll
            for (int nt = 0; nt < 2; ++nt) {
                int col = w * 32 + nt * 16 + l15;
                tvr[nt] = Tp[col] + Tp[256 + col];
            }
        }
    }

    // ---- decoder: logits = h @ Wd + bd (4-way k-split, waves 0-3) ----
    __syncthreads();                     // hnew visible; overlay free for Dp
    {
        float* Dp = (float*)(lds + OV);  // 4 waves x 64 m x 16 a = 16 KB
        if (w < 4) {
            f32x4 dacc[4];
            #pragma unroll
            for (int mi = 0; mi < 4; ++mi) dacc[mi] = (f32x4){0.f, 0.f, 0.f, 0.f};
            #pragma unroll
            for (int kh = 0; kh < 2; ++kh) {
                const int k = w * 64 + kh * 32;
                bf16x8 wdh = *(const bf16x8*)(WDh + (size_t)l15 * 256 + k + g * 8);
                bf16x8 wdl = *(const bf16x8*)(WDl + (size_t)l15 * 256 + k + g * 8);
                #pragma unroll
                for (int mi = 0; mi < 4; ++mi) {
                    int m = mi * 16 + l15;
                    int byte = m * 512 + ((k * 2 + g * 16) ^ ((m & 7) << 4));
                    bf16x8 hh = *(const bf16x8*)(hA + byte);
                    bf16x8 hl = *(const bf16x8*)(hA + HA_LO + byte);
                    dacc[mi] = __builtin_amdgcn_mfma_f32_16x16x32_bf16(wdh, hh, dacc[mi], 0, 0, 0);
                    dacc[mi] = __builtin_amdgcn_mfma_f32_16x16x32_bf16(wdl, hh, dacc[mi], 0, 0, 0);
                    dacc[mi] = __builtin_amdgcn_mfma_f32_16x16x32_bf16(wdh, hl, dacc[mi], 0, 0, 0);
                }
            }
            #pragma unroll
            for (int mi = 0; mi < 4; ++mi)
                #pragma unroll
                for (int q = 0; q < 4; ++q)
                    Dp[w * 1024 + (mi * 16 + l15) * 16 + g * 4 + q] = dacc[mi][q];
        }
    }
    __syncthreads();
    {
        float* Dp = (float*)(lds + OV);
        int m = tid >> 3, a0 = (tid & 7) * 2;
        float o0 = bd[a0], o1 = bd[a0 + 1];
        #pragma unroll
        for (int w4 = 0; w4 < 4; ++w4) {
            o0 += Dp[w4 * 1024 + m * 16 + a0];
            o1 += Dp[w4 * 1024 + m * 16 + a0 + 1];
        }
        *(float2*)(out + ((size_t)rowbase + m) * NACT + a0) = make_float2(o0, o1);
    }
}

extern "C" void kernel_launch(void* const* d_in, const int* in_sizes, int n_in,
                              void* d_out, int out_size, void* d_ws, size_t ws_size,
                              hipStream_t stream) {
    const int*   ids = (const int*)d_in[0];
    const float* emb = (const float*)d_in[1];
    const float* W1  = (const float*)d_in[2];
    const float* b1  = (const float*)d_in[3];
    const float* W2  = (const float*)d_in[4];
    const float* b2  = (const float*)d_in[5];
    const float* Wd  = (const float*)d_in[6];
    const float* bd  = (const float*)d_in[7];
    float* out = (float*)d_out;

    char* p = (char*)d_ws;
    unsigned short* WAh = (unsigned short*)p; p += 65536 * 2;
    unsigned short* WAl = (unsigned short*)p; p += 65536 * 2;
    unsigned short* WHh = (unsigned short*)p; p += 65536 * 2;
    unsigned short* WHl = (unsigned short*)p; p += 65536 * 2;
    unsigned short* WBh = (unsigned short*)p; p += 65536 * 2;
    unsigned short* WBl = (unsigned short*)p; p += 65536 * 2;
    unsigned short* WDh = (unsigned short*)p; p += 4096 * 2;
    unsigned short* WDl = (unsigned short*)p; p += 4096 * 2;
    float* Wc = (float*)p;

    prep_k<<<(PREP_N + 255) / 256, 256, 0, stream>>>(W1, W2, Wd, WAh, WAl, WHh, WHl,
                                                     WBh, WBl, WDh, WDl, Wc);
    fused_all<<<NB, 512, 0, stream>>>(ids, emb, WAh, WAl, WHh, WHl, WBh, WBl,
                                      WDh, WDl, Wc, b1, b2, bd, out);
}